// Round 2
// baseline (374.398 us; speedup 1.0000x reference)
//
#include <hip/hip_runtime.h>

// GAAPAttention: q=xWq+bq, k=xWk+bk, v=xWv+bv; attn=softmax(qk^T);
// out = ((attn v)Wa + ba) * alpha * x.   B=8, T=4096, C=128, fp32 in/out.
// Strategy: bf16 MFMA (16x16x32) for all GEMM-shaped work, fp32 softmax/accum.

typedef short short8 __attribute__((ext_vector_type(8)));
typedef float f32x4 __attribute__((ext_vector_type(4)));

constexpr int BB = 8;
constexpr int TT = 4096;
constexpr int CC = 128;

__device__ inline unsigned short f2bf(float f) {
  union { float f; unsigned int u; } c; c.f = f;
  unsigned int u = c.u;
  u += 0x7fffu + ((u >> 16) & 1u);   // RTNE
  return (unsigned short)(u >> 16);
}

// ---------------------------------------------------------------------------
// K1: fused QKV projection.  grid (256 row-tiles, 3 mats), block 256 (4 waves)
// Each block: 128 rows x 128 cols of one projection. LDS: x-tile bf16 + W^T
// bf16, both XOR-swizzled (^((row&7)<<4)) for conflict-free ds_read_b128.
// ---------------------------------------------------------------------------
__global__ __launch_bounds__(256) void qkv_kernel(
    const float* __restrict__ x,
    const float* __restrict__ Wq, const float* __restrict__ bq,
    const float* __restrict__ Wk, const float* __restrict__ bk,
    const float* __restrict__ Wv, const float* __restrict__ bv,
    unsigned short* __restrict__ Qo, unsigned short* __restrict__ Ko,
    unsigned short* __restrict__ Vo)
{
  __shared__ unsigned short xs[128 * 128];  // [row][c], 256B rows, swizzled
  __shared__ unsigned short wt[128 * 128];  // W^T: [f][c], 256B rows, swizzled
  const int t = threadIdx.x;
  const int tile = blockIdx.x;
  const int m = blockIdx.y;
  const float* W    = (m == 0) ? Wq : (m == 1) ? Wk : Wv;
  const float* bias = (m == 0) ? bq : (m == 1) ? bk : bv;
  unsigned short* out = (m == 0) ? Qo : (m == 1) ? Ko : Vo;

  // stage x tile: 128x128 fp32 -> bf16, swizzled. 4096 float4 chunks.
#pragma unroll
  for (int i = 0; i < 16; ++i) {
    int chunk = t + 256 * i;
    int row = chunk >> 5, c4 = chunk & 31;
    float4 v = *(const float4*)(x + (size_t)(tile * 128 + row) * CC + c4 * 4);
    unsigned int lo = (unsigned)f2bf(v.x) | ((unsigned)f2bf(v.y) << 16);
    unsigned int hi = (unsigned)f2bf(v.z) | ((unsigned)f2bf(v.w) << 16);
    uint2 u; u.x = lo; u.y = hi;
    unsigned int byte = (unsigned)(row * 256 + c4 * 8) ^ (((unsigned)row & 7) << 4);
    *(uint2*)((char*)xs + byte) = u;
  }
  // stage W^T: read W[c][f] coalesced, scatter bf16 to wt[f][c] (swizzled)
#pragma unroll
  for (int i = 0; i < 16; ++i) {
    int chunk = t + 256 * i;
    int c = chunk >> 5, f4 = (chunk & 31) * 4;
    float4 v = *(const float4*)(W + (size_t)c * CC + f4);
    float vv[4] = { v.x, v.y, v.z, v.w };
#pragma unroll
    for (int j = 0; j < 4; ++j) {
      int f = f4 + j;
      unsigned int byte = (unsigned)(f * 256 + c * 2) ^ (((unsigned)f & 7) << 4);
      *(unsigned short*)((char*)wt + byte) = f2bf(vv[j]);
    }
  }
  __syncthreads();

  const int w = t >> 6, l = t & 63, lr = l & 15, lh = l >> 4;
  f32x4 acc[2][8];
#pragma unroll
  for (int a = 0; a < 2; ++a)
#pragma unroll
    for (int n = 0; n < 8; ++n) acc[a][n] = (f32x4){0.f, 0.f, 0.f, 0.f};

#pragma unroll
  for (int kk = 0; kk < 4; ++kk) {
    short8 a[2];
#pragma unroll
    for (int rb = 0; rb < 2; ++rb) {
      int row = w * 32 + rb * 16 + lr;
      unsigned int byte = (unsigned)(row * 256 + kk * 64 + lh * 16) ^ (((unsigned)row & 7) << 4);
      a[rb] = *(const short8*)((const char*)xs + byte);
    }
#pragma unroll
    for (int n = 0; n < 8; ++n) {
      int row = n * 16 + lr;
      unsigned int byte = (unsigned)(row * 256 + kk * 64 + lh * 16) ^ (((unsigned)row & 7) << 4);
      short8 bfr = *(const short8*)((const char*)wt + byte);
      acc[0][n] = __builtin_amdgcn_mfma_f32_16x16x32_bf16(a[0], bfr, acc[0][n], 0, 0, 0);
      acc[1][n] = __builtin_amdgcn_mfma_f32_16x16x32_bf16(a[1], bfr, acc[1][n], 0, 0, 0);
    }
  }
  // epilogue: C/D layout row=(l>>4)*4+r, col=l&15  [m89-verified mapping]
#pragma unroll
  for (int n = 0; n < 8; ++n) {
    int col = n * 16 + lr;
    float bc = bias[col];
#pragma unroll
    for (int rb = 0; rb < 2; ++rb)
#pragma unroll
      for (int r = 0; r < 4; ++r) {
        int row = tile * 128 + w * 32 + rb * 16 + lh * 4 + r;
        out[(size_t)row * CC + col] = f2bf(acc[rb][n][r] + bc);
      }
  }
}

// ---------------------------------------------------------------------------
// K2: V transpose  V[b][t][d] -> Vt[b][d][t]  (so flash PV B-frags read
// contiguous 16B along the kv axis). grid (64 kv-tiles, 8), block 256.
// ---------------------------------------------------------------------------
__global__ __launch_bounds__(256) void vtrans_kernel(
    const unsigned short* __restrict__ V, unsigned short* __restrict__ Vt)
{
  __shared__ unsigned short tile[64 * 136]; // +8 pad
  const int t = threadIdx.x;
  const int b = blockIdx.y;
  const int kv0 = blockIdx.x * 64;
  const unsigned short* Vb = V + (size_t)b * TT * CC;
  unsigned short* Vtb = Vt + (size_t)b * TT * CC;  // [128][4096]
#pragma unroll
  for (int i = 0; i < 4; ++i) {
    int chunk = t + 256 * i;                  // 1024: 64 rows x 16 chunks
    int row = chunk >> 4, c16 = chunk & 15;
    uint4 d = *(const uint4*)(Vb + (size_t)(kv0 + row) * CC + c16 * 8);
    *(uint4*)(tile + row * 136 + c16 * 8) = d;
  }
  __syncthreads();
#pragma unroll
  for (int i = 0; i < 4; ++i) {
    int chunk = t + 256 * i;                  // 1024: 128 d x 8 kv-chunks
    int dd = chunk >> 3, kc = chunk & 7;
    unsigned short tmp[8];
#pragma unroll
    for (int j = 0; j < 8; ++j) tmp[j] = tile[(kc * 8 + j) * 136 + dd];
    uint4 u;
    u.x = (unsigned)tmp[0] | ((unsigned)tmp[1] << 16);
    u.y = (unsigned)tmp[2] | ((unsigned)tmp[3] << 16);
    u.z = (unsigned)tmp[4] | ((unsigned)tmp[5] << 16);
    u.w = (unsigned)tmp[6] | ((unsigned)tmp[7] << 16);
    *(uint4*)(Vtb + (size_t)dd * TT + kv0 + kc * 8) = u;
  }
}

// ---------------------------------------------------------------------------
// K3: flash attention (non-causal, no scale).  grid (T/64, B), block 256.
// 4 waves x 16 Q-rows each; KV tile = 32.  Q in regs; K tile + V^T tile in
// swizzled LDS; online softmax in fp32 (16-lane shuffle reduce); P staged
// through per-wave swizzled LDS for the PV A-fragment.
// ---------------------------------------------------------------------------
__global__ __launch_bounds__(256) void flash_kernel(
    const unsigned short* __restrict__ Q,
    const unsigned short* __restrict__ K,
    const unsigned short* __restrict__ Vt,
    unsigned short* __restrict__ AO)
{
  __shared__ unsigned short kt[32 * 128];   // [kv][d], 256B rows, ^((r&7)<<4)
  __shared__ unsigned short vt[128 * 32];   // [d][kv], 64B rows, ^(((r>>1)&3)<<4)
  __shared__ unsigned short ps[4 * 16 * 32];// per-wave P, 64B rows, same swz
  const int t = threadIdx.x, w = t >> 6, l = t & 63, lr = l & 15, lh = l >> 4;
  const int b = blockIdx.y;
  const int q0 = blockIdx.x * 64;
  const unsigned short* Qb  = Q  + (size_t)b * TT * CC;
  const unsigned short* Kb  = K  + (size_t)b * TT * CC;
  const unsigned short* Vtb = Vt + (size_t)b * TT * CC;
  const float LOG2E = 1.4426950408889634f;

  // Q fragments for this wave's 16 rows (A-frag: row=l&15, k=(l>>4)*8+j)
  short8 qf[4];
  {
    int qrow = q0 + w * 16 + lr;
#pragma unroll
    for (int kk = 0; kk < 4; ++kk)
      qf[kk] = *(const short8*)(Qb + (size_t)qrow * CC + kk * 32 + lh * 8);
  }
  f32x4 ao[8];
#pragma unroll
  for (int n = 0; n < 8; ++n) ao[n] = (f32x4){0.f, 0.f, 0.f, 0.f};
  float m[4], ll[4];
#pragma unroll
  for (int r = 0; r < 4; ++r) { m[r] = -1e30f; ll[r] = 0.f; }

  for (int kv0 = 0; kv0 < TT; kv0 += 32) {
    // stage K tile (32 rows x 128 d = 8 KiB): 512 16B chunks, 16 chunks/row
#pragma unroll
    for (int i = 0; i < 2; ++i) {
      int chunk = t + 256 * i;
      int row = chunk >> 4, c16 = chunk & 15;
      uint4 d = *(const uint4*)(Kb + (size_t)(kv0 + row) * CC + c16 * 8);
      unsigned int byte = (unsigned)(row * 256 + c16 * 16) ^ (((unsigned)row & 7) << 4);
      *(uint4*)((char*)kt + byte) = d;
    }
    // stage V^T tile (128 d x 32 kv = 8 KiB): 512 16B chunks, 4 chunks/row
#pragma unroll
    for (int i = 0; i < 2; ++i) {
      int chunk = t + 256 * i;
      int dd = chunk >> 2, kvc = chunk & 3;
      uint4 dv = *(const uint4*)(Vtb + (size_t)dd * TT + kv0 + kvc * 8);
      unsigned int byte = (unsigned)(dd * 64 + kvc * 16) ^ ((((unsigned)dd >> 1) & 3) << 4);
      *(uint4*)((char*)vt + byte) = dv;
    }
    __syncthreads();

    // S = Q K^T : per wave 16x32, two 16x16 D-tiles
    f32x4 s[2];
    s[0] = (f32x4){0.f, 0.f, 0.f, 0.f};
    s[1] = (f32x4){0.f, 0.f, 0.f, 0.f};
#pragma unroll
    for (int n = 0; n < 2; ++n) {
#pragma unroll
      for (int kk = 0; kk < 4; ++kk) {
        int row = n * 16 + lr;
        unsigned int byte = (unsigned)(row * 256 + kk * 64 + lh * 16) ^ (((unsigned)row & 7) << 4);
        short8 kf = *(const short8*)((const char*)kt + byte);
        s[n] = __builtin_amdgcn_mfma_f32_16x16x32_bf16(qf[kk], kf, s[n], 0, 0, 0);
      }
    }

    // online softmax: lane owns rows lh*4+r (replicated over 16 lanes)
    float sc[4], p0[4], p1[4];
#pragma unroll
    for (int r = 0; r < 4; ++r) {
      float pm = fmaxf(s[0][r], s[1][r]);
      pm = fmaxf(pm, __shfl_xor(pm, 1, 64));
      pm = fmaxf(pm, __shfl_xor(pm, 2, 64));
      pm = fmaxf(pm, __shfl_xor(pm, 4, 64));
      pm = fmaxf(pm, __shfl_xor(pm, 8, 64));
      float mnew = fmaxf(m[r], pm);
      sc[r] = exp2f((m[r] - mnew) * LOG2E);
      p0[r] = exp2f((s[0][r] - mnew) * LOG2E);
      p1[r] = exp2f((s[1][r] - mnew) * LOG2E);
      float su = p0[r] + p1[r];
      su += __shfl_xor(su, 1, 64);
      su += __shfl_xor(su, 2, 64);
      su += __shfl_xor(su, 4, 64);
      su += __shfl_xor(su, 8, 64);
      ll[r] = ll[r] * sc[r] + su;
      m[r] = mnew;
    }
#pragma unroll
    for (int n = 0; n < 8; ++n)
#pragma unroll
      for (int r = 0; r < 4; ++r) ao[n][r] *= sc[r];

    // P (16x32 bf16) -> per-wave LDS, then reload as PV A-fragment
    unsigned short* pw = ps + w * (16 * 32);
#pragma unroll
    for (int r = 0; r < 4; ++r) {
      int row = lh * 4 + r;
      unsigned int swz = ((((unsigned)row >> 1) & 3) << 4);
      *(unsigned short*)((char*)pw + ((unsigned)(row * 64 + lr * 2) ^ swz)) = f2bf(p0[r]);
      *(unsigned short*)((char*)pw + ((unsigned)(row * 64 + (16 + lr) * 2) ^ swz)) = f2bf(p1[r]);
    }
    short8 pf;
    {
      int row = lr;
      unsigned int byte = (unsigned)(row * 64 + lh * 16) ^ ((((unsigned)row >> 1) & 3) << 4);
      pf = *(const short8*)((const char*)pw + byte);
    }
    // PV: O[16x128] += P[16x32] V[32x128]
#pragma unroll
    for (int n = 0; n < 8; ++n) {
      int row = n * 16 + lr;
      unsigned int byte = (unsigned)(row * 64 + lh * 16) ^ ((((unsigned)row >> 1) & 3) << 4);
      short8 vf = *(const short8*)((const char*)vt + byte);
      ao[n] = __builtin_amdgcn_mfma_f32_16x16x32_bf16(pf, vf, ao[n], 0, 0, 0);
    }
    __syncthreads();
  }

  // epilogue: attn_out = O / l
  unsigned short* AOb = AO + (size_t)b * TT * CC;
  float inv[4];
#pragma unroll
  for (int r = 0; r < 4; ++r) inv[r] = 1.0f / ll[r];
#pragma unroll
  for (int n = 0; n < 8; ++n)
#pragma unroll
    for (int r = 0; r < 4; ++r) {
      int row = q0 + w * 16 + lh * 4 + r;
      int col = n * 16 + lr;
      AOb[(size_t)row * CC + col] = f2bf(ao[n][r] * inv[r]);
    }
}

// ---------------------------------------------------------------------------
// K4: output projection + elementwise.  out = (AO @ Wa + ba) * alpha * x
// Same GEMM structure as K1. grid 256, block 256.
// ---------------------------------------------------------------------------
__global__ __launch_bounds__(256) void outproj_kernel(
    const unsigned short* __restrict__ AO, const float* __restrict__ Wa,
    const float* __restrict__ ba, const float* __restrict__ x,
    const float* __restrict__ alpha, float* __restrict__ out)
{
  __shared__ unsigned short as_[128 * 128];
  __shared__ unsigned short wt[128 * 128];
  const int t = threadIdx.x;
  const int tile = blockIdx.x;

  // stage AO tile (already bf16): 2048 16B chunks, 16 chunks/row
#pragma unroll
  for (int i = 0; i < 8; ++i) {
    int chunk = t + 256 * i;
    int row = chunk >> 4, c16 = chunk & 15;
    uint4 d = *(const uint4*)(AO + (size_t)(tile * 128 + row) * CC + c16 * 8);
    unsigned int byte = (unsigned)(row * 256 + c16 * 16) ^ (((unsigned)row & 7) << 4);
    *(uint4*)((char*)as_ + byte) = d;
  }
  // stage Wa^T
#pragma unroll
  for (int i = 0; i < 16; ++i) {
    int chunk = t + 256 * i;
    int c = chunk >> 5, f4 = (chunk & 31) * 4;
    float4 v = *(const float4*)(Wa + (size_t)c * CC + f4);
    float vv[4] = { v.x, v.y, v.z, v.w };
#pragma unroll
    for (int j = 0; j < 4; ++j) {
      int f = f4 + j;
      unsigned int byte = (unsigned)(f * 256 + c * 2) ^ (((unsigned)f & 7) << 4);
      *(unsigned short*)((char*)wt + byte) = f2bf(vv[j]);
    }
  }
  __syncthreads();

  const int w = t >> 6, l = t & 63, lr = l & 15, lh = l >> 4;
  f32x4 acc[2][8];
#pragma unroll
  for (int a = 0; a < 2; ++a)
#pragma unroll
    for (int n = 0; n < 8; ++n) acc[a][n] = (f32x4){0.f, 0.f, 0.f, 0.f};

#pragma unroll
  for (int kk = 0; kk < 4; ++kk) {
    short8 a[2];
#pragma unroll
    for (int rb = 0; rb < 2; ++rb) {
      int row = w * 32 + rb * 16 + lr;
      unsigned int byte = (unsigned)(row * 256 + kk * 64 + lh * 16) ^ (((unsigned)row & 7) << 4);
      a[rb] = *(const short8*)((const char*)as_ + byte);
    }
#pragma unroll
    for (int n = 0; n < 8; ++n) {
      int row = n * 16 + lr;
      unsigned int byte = (unsigned)(row * 256 + kk * 64 + lh * 16) ^ (((unsigned)row & 7) << 4);
      short8 bfr = *(const short8*)((const char*)wt + byte);
      acc[0][n] = __builtin_amdgcn_mfma_f32_16x16x32_bf16(a[0], bfr, acc[0][n], 0, 0, 0);
      acc[1][n] = __builtin_amdgcn_mfma_f32_16x16x32_bf16(a[1], bfr, acc[1][n], 0, 0, 0);
    }
  }

  const float a0 = alpha[0];
#pragma unroll
  for (int n = 0; n < 8; ++n) {
    int col = n * 16 + lr;
    float bc = ba[col];
#pragma unroll
    for (int rb = 0; rb < 2; ++rb)
#pragma unroll
      for (int r = 0; r < 4; ++r) {
        int row = tile * 128 + w * 32 + rb * 16 + lh * 4 + r;
        size_t idx = (size_t)row * CC + col;
        out[idx] = (acc[rb][n][r] + bc) * a0 * x[idx];
      }
  }
}

// ---------------------------------------------------------------------------
extern "C" void kernel_launch(void* const* d_in, const int* in_sizes, int n_in,
                              void* d_out, int out_size, void* d_ws, size_t ws_size,
                              hipStream_t stream) {
  const float* x     = (const float*)d_in[0];
  const float* Wq    = (const float*)d_in[1];
  const float* bq    = (const float*)d_in[2];
  const float* Wk    = (const float*)d_in[3];
  const float* bk    = (const float*)d_in[4];
  const float* Wv    = (const float*)d_in[5];
  const float* bv    = (const float*)d_in[6];
  const float* Wa    = (const float*)d_in[7];
  const float* ba    = (const float*)d_in[8];
  const float* alpha = (const float*)d_in[9];
  float* out = (float*)d_out;

  char* ws = (char*)d_ws;
  const size_t MAT = (size_t)BB * TT * CC * sizeof(unsigned short); // 8 MiB
  unsigned short* Q  = (unsigned short*)(ws);
  unsigned short* K  = (unsigned short*)(ws + MAT);
  unsigned short* V  = (unsigned short*)(ws + 2 * MAT);
  unsigned short* Vt = (unsigned short*)(ws + 3 * MAT);
  unsigned short* AO = (unsigned short*)(ws + 2 * MAT);  // alias V (dead after vtrans)

  qkv_kernel<<<dim3(256, 3), 256, 0, stream>>>(x, Wq, bq, Wk, bk, Wv, bv, Q, K, V);
  vtrans_kernel<<<dim3(64, 8), 256, 0, stream>>>(V, Vt);
  flash_kernel<<<dim3(64, 8), 256, 0, stream>>>(Q, K, Vt, AO);
  outproj_kernel<<<dim3(256), 256, 0, stream>>>(AO, Wa, ba, x, alpha, out);
}